// Round 12
// baseline (43.266 us; speedup 1.0000x reference)
//
#include <hip/hip_runtime.h>
#include <math.h>

#define NEG_SLOPE 0.2f
#define LOG2E 1.44269504088896f

#if __has_builtin(__builtin_amdgcn_exp2f)
#define EXP2F __builtin_amdgcn_exp2f
#else
#define EXP2F exp2f
#endif

typedef _Float16 f16x8 __attribute__((ext_vector_type(8)));
typedef __fp16 h16x2 __attribute__((ext_vector_type(2)));   // cvt_pkrtz native type
typedef float f32x4 __attribute__((ext_vector_type(4)));
typedef float f32x2 __attribute__((ext_vector_type(2)));

union PK8 { uint4 u4; _Float16 h[8]; f16x8 v; h16x2 p[4]; };
union PK1 { unsigned short u; _Float16 h; };

#define WN_CHUNKS (256 * 256 / 8)        // 8192 W-chunks of 8

// ---------------------------------------------------------------------------
// Kernel 0: one-shot f32 -> f16 convert of W (131 KB). 32 blocks.
// ---------------------------------------------------------------------------
__global__ __launch_bounds__(256) void cvt_w(const float* __restrict__ W,
                                             unsigned short* __restrict__ wf) {
    int idx = blockIdx.x * 256 + threadIdx.x;
    if (idx >= WN_CHUNKS) return;
    const float* src = W + (size_t)idx * 8;
    float4 v0 = *(const float4*)(src);
    float4 v1 = *(const float4*)(src + 4);
    PK8 p;
    p.p[0] = __builtin_amdgcn_cvt_pkrtz(v0.x, v0.y);
    p.p[1] = __builtin_amdgcn_cvt_pkrtz(v0.z, v0.w);
    p.p[2] = __builtin_amdgcn_cvt_pkrtz(v1.x, v1.y);
    p.p[3] = __builtin_amdgcn_cvt_pkrtz(v1.z, v1.w);
    *(uint4*)(wf + (size_t)idx * 8) = p.u4;
}

// ---------------------------------------------------------------------------
// Kernel A: Wx = x @ W.T via f16 MFMA; ALSO computes s_src/s_tgt from the
// f32 accumulators (in-register dot + shfl-reduce over ln) -> tiny globals.
// Output f16 [bh][d][j] -> wxtg. Grid 1024: m0=(bid&255)*64, n0=(bid>>8)*64.
// ---------------------------------------------------------------------------
__global__ __launch_bounds__(256) void gemm_wxt(const float* __restrict__ x,
                                                const unsigned short* __restrict__ wf,
                                                const float* __restrict__ attn,
                                                unsigned short* __restrict__ wxtg,
                                                float* __restrict__ s_src,
                                                float* __restrict__ s_tgt) {
    __shared__ __align__(16) unsigned short xs[64 * 64];    // [i][k] f16, row 128B
    __shared__ __align__(16) unsigned short pool[64 * 64];  // ws / tb alias, 8KB
    unsigned short* ws = pool;   // [n][k] f16, row 128B, swz (n&7)<<4
    unsigned short* tb = pool;   // [n][j] f16, row 128B, swz (n&7)<<4 (after GEMM)

    const int tid = threadIdx.x;
    const int bid = blockIdx.x;
    const int m0 = (bid & 255) * 64;
    const int n0 = (bid >> 8) * 64;
    const int w = tid >> 6, l = tid & 63;
    const int q = l >> 4, ln = l & 15;
    const int iw = (w & 1) * 32, nw = (w >> 1) * 32;

    f32x4 acc[2][2];
    #pragma unroll
    for (int g = 0; g < 2; ++g)
        #pragma unroll
        for (int t = 0; t < 2; ++t) acc[g][t] = (f32x4){0.f, 0.f, 0.f, 0.f};

    for (int kc = 0; kc < 256; kc += 64) {
        __syncthreads();
        // stage x tile 64x64 f32 -> f16 (16 elems/thread, packed cvt)
        {
            const int i = tid >> 2, kq = tid & 3;
            const float* src = x + (size_t)(m0 + i) * 256 + kc + kq * 16;
            float4 v0 = *(const float4*)(src + 0);
            float4 v1 = *(const float4*)(src + 4);
            float4 v2 = *(const float4*)(src + 8);
            float4 v3 = *(const float4*)(src + 12);
            PK8 p0, p1;
            p0.p[0] = __builtin_amdgcn_cvt_pkrtz(v0.x, v0.y);
            p0.p[1] = __builtin_amdgcn_cvt_pkrtz(v0.z, v0.w);
            p0.p[2] = __builtin_amdgcn_cvt_pkrtz(v1.x, v1.y);
            p0.p[3] = __builtin_amdgcn_cvt_pkrtz(v1.z, v1.w);
            p1.p[0] = __builtin_amdgcn_cvt_pkrtz(v2.x, v2.y);
            p1.p[1] = __builtin_amdgcn_cvt_pkrtz(v2.z, v2.w);
            p1.p[2] = __builtin_amdgcn_cvt_pkrtz(v3.x, v3.y);
            p1.p[3] = __builtin_amdgcn_cvt_pkrtz(v3.z, v3.w);
            int b0 = i * 128 + kq * 32;
            *(uint4*)((char*)xs + (b0 ^ ((i & 7) << 4))) = p0.u4;
            *(uint4*)((char*)xs + ((b0 + 16) ^ ((i & 7) << 4))) = p1.u4;
        }
        // stage W tile 64x64 u16: 512 uint4, 2/thread
        #pragma unroll
        for (int p = 0; p < 2; ++p) {
            int idx = p * 256 + tid;
            int n = idx >> 3, c = idx & 7;
            uint4 v = *(const uint4*)(wf + (size_t)(n0 + n) * 256 + kc + c * 8);
            *(uint4*)((char*)ws + ((n * 128 + c * 16) ^ ((n & 7) << 4))) = v;
        }
        __syncthreads();

        #pragma unroll
        for (int ks = 0; ks < 2; ++ks) {
            const int kb = ks * 64 + q * 16;
            f16x8 af[2];
            #pragma unroll
            for (int g = 0; g < 2; ++g) {
                int row = iw + g * 16 + ln;
                uint4 raw = *(const uint4*)((const char*)xs +
                            ((row * 128 + kb) ^ ((row & 7) << 4)));
                PK8 pk; pk.u4 = raw;
                af[g] = pk.v;
            }
            #pragma unroll
            for (int t = 0; t < 2; ++t) {
                int n = nw + t * 16 + ln;
                uint4 raw = *(const uint4*)((const char*)ws +
                            ((n * 128 + kb) ^ ((n & 7) << 4)));
                PK8 pk; pk.u4 = raw;
                f16x8 bf = pk.v;
                acc[0][t] = __builtin_amdgcn_mfma_f32_16x16x32_f16(af[0], bf, acc[0][t], 0, 0, 0);
                acc[1][t] = __builtin_amdgcn_mfma_f32_16x16x32_f16(af[1], bf, acc[1][t], 0, 0, 0);
            }
        }
    }

    // ---- scores epilogue: s[j] = sum_d Wx[j][d]*a[d] from acc fragments ----
    // C layout: row(i-local) = iw + g*16 + q*4 + r, col(n-local) = nw + t*16 + ln.
    {
        const int h = (n0 + nw) >> 5;            // this wave's head
        float avs[2], avt[2];
        #pragma unroll
        for (int t = 0; t < 2; ++t) {
            avs[t] = attn[h * 64 + t * 16 + ln];         // d = t*16 + ln
            avt[t] = attn[h * 64 + 32 + t * 16 + ln];
        }
        const int bb = m0 >> 9;
        const int jbase = (m0 & 511) + iw;
        const int bh = bb * 8 + h;
        #pragma unroll
        for (int g = 0; g < 2; ++g)
            #pragma unroll
            for (int r = 0; r < 4; ++r) {
                float ps = acc[g][0][r] * avs[0] + acc[g][1][r] * avs[1];
                float pt = acc[g][0][r] * avt[0] + acc[g][1][r] * avt[1];
                ps += __shfl_xor(ps, 1); ps += __shfl_xor(ps, 2);
                ps += __shfl_xor(ps, 4); ps += __shfl_xor(ps, 8);
                pt += __shfl_xor(pt, 1); pt += __shfl_xor(pt, 2);
                pt += __shfl_xor(pt, 4); pt += __shfl_xor(pt, 8);
                if (ln == 0) {
                    int j = jbase + g * 16 + q * 4 + r;
                    s_src[bh * 512 + j] = ps;
                    s_tgt[bh * 512 + j] = pt;
                }
            }
    }

    __syncthreads();   // done reading ws -> tb may overwrite
    // C frags -> transpose buffer tb[n][j_local] f16
    #pragma unroll
    for (int g = 0; g < 2; ++g)
        #pragma unroll
        for (int t = 0; t < 2; ++t)
            #pragma unroll
            for (int r = 0; r < 4; ++r) {
                int n  = nw + t * 16 + ln;            // C col
                int jl = iw + g * 16 + q * 4 + r;     // C row
                PK1 hv; hv.h = (_Float16)acc[g][t][r];
                *(unsigned short*)((char*)tb + ((n * 128 + jl * 2) ^ ((n & 7) << 4))) = hv.u;
            }
    __syncthreads();
    // coalesced readout: 512 16B chunks, 2/thread
    {
        const int bb = m0 >> 9, j0 = m0 & 511;
        #pragma unroll
        for (int p = 0; p < 2; ++p) {
            int idx = p * 256 + tid;
            int n = idx >> 3, c = idx & 7;
            uint4 v = *(const uint4*)((const char*)tb + ((n * 128 + c * 16) ^ ((n & 7) << 4)));
            int nn = n0 + n;                          // = h*32 + d
            *(uint4*)(wxtg + ((size_t)(bb * 256 + nn) * 512 + j0 + c * 8)) = v;
        }
    }
}

// ---------------------------------------------------------------------------
// Kernel B: softmax + PV + ELU, LDS-minimal. Grid 512 = (half, b, h).
// 512 thr = 8 waves; wave owns 32 i-rows (g=2). NO WxT LDS: bf fragments
// loaded straight from wxtg (L2/L3-hot, base ptr + imm offsets). Only stf
// (2KB) in LDS. ONE barrier; main loop is pure barrier-free dataflow.
// ---------------------------------------------------------------------------
__global__ __launch_bounds__(512, 4) void gat_attn(const unsigned short* __restrict__ wxtg,
                                                   const float* __restrict__ s_src,
                                                   const float* __restrict__ s_tgt,
                                                   float* __restrict__ out) {
    __shared__ float stf[512];    // s_tgt * LOG2E
    __shared__ float red_s[8];

    const int bid = blockIdx.x;
    const int bh = bid & 255, half = bid >> 8;
    const int b = bh >> 3, h = bh & 7;
    const int tid = threadIdx.x;
    const int w = tid >> 6, l = tid & 63;
    const int q = l >> 4, ln = l & 15;

    // ---- stage stf + block max (one coalesced f32 load per thread) ----
    {
        float stv = s_tgt[bh * 512 + tid] * LOG2E;
        stf[tid] = stv;
        float m = stv;
        #pragma unroll
        for (int off = 32; off > 0; off >>= 1)
            m = fmaxf(m, __shfl_xor(m, off));
        if (l == 0) red_s[w] = m;
    }
    __syncthreads();
    float maxtK = red_s[0];
    #pragma unroll
    for (int ww = 1; ww < 8; ++ww) maxtK = fmaxf(maxtK, red_s[ww]);

    // ---- wave owns rows i = half*256 + w*32 + g*16 + ln ----
    const int ibase = half * 256 + w * 32;
    float ciK[2], miK[2];
    #pragma unroll
    for (int g = 0; g < 2; ++g) {
        float cc = s_src[bh * 512 + ibase + g * 16 + ln] * LOG2E;
        float cm = cc + maxtK;
        miK[g] = fmaxf(cm, NEG_SLOPE * cm);
        ciK[g] = cc;
    }

    // per-lane bf base pointers (row d = dt*16+ln, col q*8; kk adds 32 elems)
    const unsigned short* pb0 = wxtg + (size_t)bh * 16384 + ln * 512 + q * 8;
    const unsigned short* pb1 = pb0 + 16 * 512;

    f32x4 acc[2][2];
    #pragma unroll
    for (int g = 0; g < 2; ++g) {
        acc[g][0] = (f32x4){0.f, 0.f, 0.f, 0.f};
        acc[g][1] = (f32x4){0.f, 0.f, 0.f, 0.f};
    }
    f32x2 pdv[2] = {(f32x2){0.f, 0.f}, (f32x2){0.f, 0.f}};

    #pragma unroll 2
    for (int kk = 0; kk < 16; ++kk) {
        f16x8 bf[2];
        {
            PK8 pk0, pk1;
            pk0.u4 = *(const uint4*)(pb0 + kk * 32);
            pk1.u4 = *(const uint4*)(pb1 + kk * 32);
            bf[0] = pk0.v;
            bf[1] = pk1.v;
        }
        const int j0 = kk * 32 + q * 8;
        f32x2 stp[4];
        {
            float4 s0 = *(const float4*)(stf + j0);
            float4 s1 = *(const float4*)(stf + j0 + 4);
            stp[0] = (f32x2){s0.x, s0.y};
            stp[1] = (f32x2){s0.z, s0.w};
            stp[2] = (f32x2){s1.x, s1.y};
            stp[3] = (f32x2){s1.z, s1.w};
        }

        #pragma unroll
        for (int g = 0; g < 2; ++g) {
            const f32x2 ci2 = (f32x2){ciK[g], ciK[g]};
            const f32x2 mi2 = (f32x2){miK[g], miK[g]};
            PK8 pa;
            #pragma unroll
            for (int pr = 0; pr < 4; ++pr) {
                f32x2 e  = ci2 + stp[pr];                           // v_pk_add
                f32x2 a1 = e - mi2;                                 // v_pk_add(-)
                f32x2 a2 = (f32x2){NEG_SLOPE, NEG_SLOPE} * e - mi2; // v_pk_fma
                float m0 = fmaxf(a1.x, a2.x);
                float m1 = fmaxf(a1.y, a2.y);
                float p0 = EXP2F(m0);
                float p1 = EXP2F(m1);
                pdv[g] += (f32x2){p0, p1};                          // v_pk_add
                pa.p[pr] = __builtin_amdgcn_cvt_pkrtz(p0, p1);      // 1 cvt
            }
            acc[g][0] = __builtin_amdgcn_mfma_f32_16x16x32_f16(pa.v, bf[0], acc[g][0], 0, 0, 0);
            acc[g][1] = __builtin_amdgcn_mfma_f32_16x16x32_f16(pa.v, bf[1], acc[g][1], 0, 0, 0);
        }
    }

    float inv[2];
    #pragma unroll
    for (int g = 0; g < 2; ++g) {
        float s = pdv[g].x + pdv[g].y;
        s += __shfl_xor(s, 16);
        s += __shfl_xor(s, 32);
        inv[g] = 1.f / s;
    }
    #pragma unroll
    for (int g = 0; g < 2; ++g)
        #pragma unroll
        for (int dt = 0; dt < 2; ++dt)
            #pragma unroll
            for (int r = 0; r < 4; ++r) {
                int row = q * 4 + r;
                float dn = __shfl(inv[g], row);    // lane 'row' holds denom for i-local=row
                float o = acc[g][dt][r] * dn;
                o = o > 0.f ? o : (__expf(o) - 1.f);
                size_t i = (size_t)(b * 512 + ibase + g * 16 + row);
                out[i * 256 + h * 32 + dt * 16 + ln] = o;
            }
}

// ---------------------------------------------------------------------------
extern "C" void kernel_launch(void* const* d_in, const int* in_sizes, int n_in,
                              void* d_out, int out_size, void* d_ws, size_t ws_size,
                              hipStream_t stream) {
    const float* x    = (const float*)d_in[0];   // (32,512,256)
    const float* W    = (const float*)d_in[1];   // (256,256)
    const float* attn = (const float*)d_in[2];   // (1,8,64)
    float* out = (float*)d_out;                  // (32,512,256)

    unsigned short* wf   = (unsigned short*)d_ws;             // f16 W, 131 KB
    unsigned short* wxtg = wf + 256 * 256;                    // f16 [bh][d][j], 8.39 MB
    float* s_src = (float*)(wxtg + (size_t)256 * 32 * 512);   // [bh][j] f32, 524 KB
    float* s_tgt = s_src + 256 * 512;                         // [bh][j] f32, 524 KB

    cvt_w<<<WN_CHUNKS / 256, 256, 0, stream>>>(W, wf);
    gemm_wxt<<<1024, 256, 0, stream>>>(x, wf, attn, wxtg, s_src, s_tgt);
    gat_attn<<<512, 512, 0, stream>>>(wxtg, s_src, s_tgt, out);
}